// Round 9
// baseline (3723.427 us; speedup 1.0000x reference)
//
#include <hip/hip_runtime.h>

#define LAMBDA_INIT 0.2f
#define SCALING 0.17677669529663687f   // 1/sqrt(32)
#define EPS_DEF 1.1920928955078125e-07f
#define EPS_ATTN 1e-5f

typedef unsigned short us4 __attribute__((ext_vector_type(4)));
typedef float f32x4 __attribute__((ext_vector_type(4)));

__device__ __forceinline__ float bf2f(unsigned short u) {
    unsigned int x = ((unsigned int)u) << 16;
    return __builtin_bit_cast(float, x);
}
__device__ __forceinline__ unsigned short f2bf(float f) {
    unsigned int x = __builtin_bit_cast(unsigned int, f);
    x += 0x7fffu + ((x >> 16) & 1u);
    return (unsigned short)(x >> 16);
}

__device__ __forceinline__ float wave_sum(float v) {
#pragma unroll
    for (int o = 32; o > 0; o >>= 1) v += __shfl_down(v, o);
    return v;
}
__device__ __forceinline__ float wave_max(float v) {
#pragma unroll
    for (int o = 32; o > 0; o >>= 1) v = fmaxf(v, __shfl_down(v, o));
    return v;
}
__device__ __forceinline__ float block_sum(float v, float* red4) {
    int wv = threadIdx.x >> 6;
    float w = wave_sum(v);
    __syncthreads();
    if ((threadIdx.x & 63) == 0) red4[wv] = w;
    __syncthreads();
    return red4[0] + red4[1] + red4[2] + red4[3];
}
__device__ __forceinline__ float block_max(float v, float* red4) {
    int wv = threadIdx.x >> 6;
    float w = wave_max(v);
    __syncthreads();
    if ((threadIdx.x & 63) == 0) red4[wv] = w;
    __syncthreads();
    return fmaxf(fmaxf(red4[0], red4[1]), fmaxf(red4[2], red4[3]));
}

// ---------------- prep: zero G, compute lambda ----------------
__global__ __launch_bounds__(256) void prep(float* __restrict__ G, float* __restrict__ lamp,
                                            const float* lq1, const float* lk1,
                                            const float* lq2, const float* lk2) {
    int i = (blockIdx.x * 256 + threadIdx.x) * 4;
    G[i] = 0.f; G[i + 1] = 0.f; G[i + 2] = 0.f; G[i + 3] = 0.f;
    if (blockIdx.x == 0 && threadIdx.x == 0) {
        float a = 0.f, c = 0.f;
        for (int d = 0; d < 32; d++) {
            a += lq1[d] * lk1[d];
            c += lq2[d] * lk2[d];
        }
        *lamp = expf(a) - expf(c) + LAMBDA_INIT;
    }
}

// ---------------- RMSNorm: fp32 in, fp32 weight, fp32 or bf16 out ----------------
template <int OUTBF>
__global__ __launch_bounds__(256) void rms_kernel(const float* __restrict__ x,
                                                  const float* __restrict__ w,
                                                  void* __restrict__ out, float eps) {
    int row = blockIdx.x;
    int tid = threadIdx.x;
    size_t base = (size_t)row * 1024 + tid * 4;
    f32x4 v = *(const f32x4*)(x + base);
    float ss = v[0]*v[0] + v[1]*v[1] + v[2]*v[2] + v[3]*v[3];
    __shared__ float red4[4];
    float tot = block_sum(ss, red4);
    float r = rsqrtf(tot * (1.0f / 1024.f) + eps);
    f32x4 wv = *(const f32x4*)(w + tid * 4);
#pragma unroll
    for (int i = 0; i < 4; i++) {
        float val = v[i] * r * wv[i];
        if (OUTBF) ((unsigned short*)out)[base + i] = f2bf(val);
        else ((float*)out)[base + i] = val;
    }
}

// ---------------- VALU fp32 GEMM: C[M,N] = A[M,K] @ Bt[N,K]^T + bias ----------------
// A: fp32 or bf16 (internal). Bt/bias/res: fp32. MODE 0: fp32 out. 1: fp32 out + fp32 res.
template <typename AT, int MODE>
__global__ __launch_bounds__(256) void gemm_v(const AT* __restrict__ A,
                                              const float* __restrict__ Bt,
                                              const float* __restrict__ bias,
                                              const float* __restrict__ res,
                                              float* __restrict__ out, int M, int N, int K) {
    __shared__ __align__(16) float As[16][68];
    __shared__ __align__(16) float Bs[16][68];
    const int tid = threadIdx.x;
    const int bm = blockIdx.x, bn = blockIdx.y;
    const int tx = tid & 15, ty = tid >> 4;
    const int r = tid >> 2, c = (tid & 3) * 4;
    const AT* Ap = A + (size_t)(bm * 64 + r) * K + c;
    const float* Bp = Bt + (size_t)(bn * 64 + r) * K + c;
    float acc[4][4] = {{0.f}};
    for (int k0 = 0; k0 < K; k0 += 16) {
        float a0, a1, a2, a3;
        if constexpr (sizeof(AT) == 2) {
            us4 av = *(const us4*)(Ap + k0);
            a0 = bf2f(av[0]); a1 = bf2f(av[1]); a2 = bf2f(av[2]); a3 = bf2f(av[3]);
        } else {
            f32x4 av = *(const f32x4*)(Ap + k0);
            a0 = av[0]; a1 = av[1]; a2 = av[2]; a3 = av[3];
        }
        f32x4 bv4 = *(const f32x4*)(Bp + k0);
        __syncthreads();
        As[c + 0][r] = a0; As[c + 1][r] = a1; As[c + 2][r] = a2; As[c + 3][r] = a3;
        Bs[c + 0][r] = bv4[0]; Bs[c + 1][r] = bv4[1]; Bs[c + 2][r] = bv4[2]; Bs[c + 3][r] = bv4[3];
        __syncthreads();
#pragma unroll
        for (int kk = 0; kk < 16; kk++) {
            f32x4 av = *(const f32x4*)&As[kk][ty * 4];
            f32x4 bv = *(const f32x4*)&Bs[kk][tx * 4];
#pragma unroll
            for (int i = 0; i < 4; i++)
#pragma unroll
                for (int j = 0; j < 4; j++)
                    acc[i][j] = fmaf(av[i], bv[j], acc[i][j]);
        }
    }
#pragma unroll
    for (int i = 0; i < 4; i++) {
        int m = bm * 64 + ty * 4 + i;
#pragma unroll
        for (int j = 0; j < 4; j++) {
            int n = bn * 64 + tx * 4 + j;
            size_t oi = (size_t)m * N + n;
            float v = acc[i][j] + bias[n];
            if (MODE == 0) out[oi] = v;
            else out[oi] = v + res[oi];
        }
    }
}

// ---------------- fused gate GEMM: mlp = (h2@Wu^T+bu) * silu(h2@Wv^T+bv) ----------------
__global__ __launch_bounds__(256) void gemm_gate_v(const unsigned short* __restrict__ A,
                                                   const float* __restrict__ Wg,
                                                   const float* __restrict__ bg,
                                                   unsigned short* __restrict__ mlp) {
    __shared__ __align__(16) float As[16][68];
    __shared__ __align__(16) float BsU[16][68];
    __shared__ __align__(16) float BsV[16][68];
    const int tid = threadIdx.x;
    const int bm = blockIdx.x, bn = blockIdx.y;
    const int tx = tid & 15, ty = tid >> 4;
    const int r = tid >> 2, c = (tid & 3) * 4;
    const unsigned short* Ap = A + (size_t)(bm * 64 + r) * 1024 + c;
    const float* BpU = Wg + (size_t)(bn * 64 + r) * 1024 + c;
    const float* BpV = Wg + (size_t)(4096 + bn * 64 + r) * 1024 + c;
    float accU[4][4] = {{0.f}}, accV[4][4] = {{0.f}};
    for (int k0 = 0; k0 < 1024; k0 += 16) {
        us4 avw = *(const us4*)(Ap + k0);
        f32x4 u4 = *(const f32x4*)(BpU + k0);
        f32x4 v4 = *(const f32x4*)(BpV + k0);
        __syncthreads();
        As[c + 0][r] = bf2f(avw[0]); As[c + 1][r] = bf2f(avw[1]);
        As[c + 2][r] = bf2f(avw[2]); As[c + 3][r] = bf2f(avw[3]);
        BsU[c + 0][r] = u4[0]; BsU[c + 1][r] = u4[1]; BsU[c + 2][r] = u4[2]; BsU[c + 3][r] = u4[3];
        BsV[c + 0][r] = v4[0]; BsV[c + 1][r] = v4[1]; BsV[c + 2][r] = v4[2]; BsV[c + 3][r] = v4[3];
        __syncthreads();
#pragma unroll
        for (int kk = 0; kk < 16; kk++) {
            f32x4 av = *(const f32x4*)&As[kk][ty * 4];
            f32x4 uv = *(const f32x4*)&BsU[kk][tx * 4];
            f32x4 vv = *(const f32x4*)&BsV[kk][tx * 4];
#pragma unroll
            for (int i = 0; i < 4; i++)
#pragma unroll
                for (int j = 0; j < 4; j++) {
                    accU[i][j] = fmaf(av[i], uv[j], accU[i][j]);
                    accV[i][j] = fmaf(av[i], vv[j], accV[i][j]);
                }
        }
    }
#pragma unroll
    for (int i = 0; i < 4; i++) {
        int m = bm * 64 + ty * 4 + i;
#pragma unroll
        for (int j = 0; j < 4; j++) {
            int n = bn * 64 + tx * 4 + j;
            float u = accU[i][j] + bg[n];
            float v = accV[i][j] + bg[4096 + n];
            float s = v / (1.f + __expf(-v));
            mlp[(size_t)m * 4096 + n] = f2bf(u * s);
        }
    }
}

// ---------------- RoPE in place, token order ----------------
__global__ __launch_bounds__(256) void rope_inplace(float* __restrict__ Y,
                                                    const float* __restrict__ fc) {
    int t = blockIdx.x;
    int s = t & 1023;
    int p = s >> 2;
    if (p == 0) return;
    int c0 = threadIdx.x * 4;
    float* y = Y + (size_t)t * 1024 + c0;
    int d4 = (c0 & 31) >> 1;
    f32x4 f = *(const f32x4*)(fc + ((size_t)(p - 1) * 16 + d4) * 2);  // [cos,sin,cos,sin]
    float v0 = y[0], v1 = y[1], v2 = y[2], v3 = y[3];
    y[0] = v0 * f[0] - v1 * f[1];
    y[1] = v0 * f[1] + v1 * f[0];
    y[2] = v2 * f[2] - v3 * f[3];
    y[3] = v2 * f[3] + v3 * f[2];
}

// ---------------- pass A: G[b][h][k'] = sum_{q'} a1[q'][k']  (token-order Q/K) ----------------
__global__ __launch_bounds__(256) void pass_a(const float* __restrict__ Yq,
                                              const float* __restrict__ Yk,
                                              float* __restrict__ G) {
    int qc = blockIdx.x, h = blockIdx.y, b = blockIdx.z;
    int tid = threadIdx.x;
    const float* Yqb = Yq + (size_t)b * 1024 * 1024;
    const float* Ykb = Yk + (size_t)b * 1024 * 1024;
    __shared__ float qv[32];
    __shared__ float red4[4];
    float ga[4] = {0.f, 0.f, 0.f, 0.f};
    int j0 = tid * 4;
    const float* krow[4];
#pragma unroll
    for (int kk = 0; kk < 4; kk++) {
        int j = j0 + kk;
        int tk = (j & 255) * 4 + (j >> 8);
        krow[kk] = Ykb + (size_t)tk * 1024 + h * 64;
    }
    for (int qi = 0; qi < 64; qi++) {
        int qp = qc * 64 + qi;
        int pq = qp & 255;
        int tq = pq * 4 + (qp >> 8);
        __syncthreads();
        if (tid < 32) qv[tid] = Yqb[(size_t)tq * 1024 + h * 64 + tid];
        __syncthreads();
        float sc[4], la[4];
        bool msk[4];
        float lmax = 0.f;
#pragma unroll
        for (int kk = 0; kk < 4; kk++) {
            const f32x4* kr = (const f32x4*)krow[kk];
            float dot = 0.f;
#pragma unroll
            for (int c = 0; c < 8; c++) {
                f32x4 kvv = kr[c];
#pragma unroll
                for (int u = 0; u < 4; u++) dot += qv[c * 4 + u] * kvv[u];
            }
            sc[kk] = dot * SCALING;
            msk[kk] = ((j0 + kk) & 255) > pq;
            la[kk] = fabsf(sc[kk]);
            if (!msk[kk]) lmax = fmaxf(lmax, la[kk]);
        }
        float M = block_max(lmax, red4);
        float ls = 0.f;
        float e[4];
#pragma unroll
        for (int kk = 0; kk < 4; kk++) {
            e[kk] = msk[kk] ? 0.f : __expf(la[kk] - M);
            ls += e[kk];
        }
        float Z = block_sum(ls, red4);
        float inv = 1.f / fmaxf(Z, 1e-20f);
#pragma unroll
        for (int kk = 0; kk < 4; kk++) {
            float s = sc[kk];
            float sg = (s > 0.f) ? 1.f : ((s < 0.f) ? -1.f : 0.f);
            ga[kk] += sg * e[kk] * inv;
        }
    }
#pragma unroll
    for (int kk = 0; kk < 4; kk++)
        atomicAdd(&G[(((size_t)b * 16 + h) << 10) + j0 + kk], ga[kk]);
}

// ---------------- pass B: attention row q', AV, RMS, reshape-store ----------------
__global__ __launch_bounds__(256) void pass_b(const float* __restrict__ Yq,
                                              const float* __restrict__ Yk,
                                              const float* __restrict__ Yv,
                                              const float* __restrict__ G,
                                              const float* __restrict__ lamp,
                                              const float* __restrict__ wan,
                                              unsigned short* __restrict__ aoS) {
    int qp = blockIdx.x, h = blockIdx.y, b = blockIdx.z;
    int tid = threadIdx.x;
    int pq = qp & 255;
    int tq = pq * 4 + (qp >> 8);
    const float* Yqb = Yq + (size_t)b * 1024 * 1024;
    const float* Ykb = Yk + (size_t)b * 1024 * 1024;
    __shared__ float qbuf[64];
    __shared__ float arow[1024];
    __shared__ float pr[256];
    __shared__ float red4[4];
    if (tid < 64) qbuf[tid] = Yqb[(size_t)tq * 1024 + h * 64 + tid];
    __syncthreads();
    int j0 = tid * 4;
    float s1[4], s2[4], l1[4], l2[4];
    bool msk[4];
    float m1 = 0.f, m2 = 0.f;
#pragma unroll
    for (int kk = 0; kk < 4; kk++) {
        int j = j0 + kk;
        int tk = (j & 255) * 4 + (j >> 8);
        const f32x4* kb = (const f32x4*)(Ykb + (size_t)tk * 1024 + h * 64);
        float d1 = 0.f, d2 = 0.f;
#pragma unroll
        for (int c = 0; c < 8; c++) {
            f32x4 k1 = kb[c], k2 = kb[8 + c];
#pragma unroll
            for (int u = 0; u < 4; u++) {
                d1 += qbuf[c * 4 + u] * k1[u];
                d2 += qbuf[32 + c * 4 + u] * k2[u];
            }
        }
        s1[kk] = d1 * SCALING;
        s2[kk] = d2 * SCALING;
        msk[kk] = (j & 255) > pq;
        l1[kk] = fabsf(s1[kk]);
        l2[kk] = fabsf(s2[kk]);
        if (!msk[kk]) { m1 = fmaxf(m1, l1[kk]); m2 = fmaxf(m2, l2[kk]); }
    }
    float M1 = block_max(m1, red4);
    float M2 = block_max(m2, red4);
    float ls1 = 0.f, ls2 = 0.f;
    float e1[4], e2[4];
#pragma unroll
    for (int kk = 0; kk < 4; kk++) {
        e1[kk] = msk[kk] ? 0.f : __expf(l1[kk] - M1); ls1 += e1[kk];
        e2[kk] = msk[kk] ? 0.f : __expf(l2[kk] - M2); ls2 += e2[kk];
    }
    float Z1 = block_sum(ls1, red4);
    float Z2 = block_sum(ls2, red4);
    float i1 = 1.f / fmaxf(Z1, 1e-20f), i2 = 1.f / fmaxf(Z2, 1e-20f);
    float lam = *lamp;
    const float* Gb = G + (((size_t)b * 16 + h) << 10);
#pragma unroll
    for (int kk = 0; kk < 4; kk++) {
        int j = j0 + kk;
        float a;
        if (msk[kk]) a = 0.f;
        else {
            float sg1 = (s1[kk] > 0.f) ? 1.f : ((s1[kk] < 0.f) ? -1.f : 0.f);
            float sg2 = (s2[kk] > 0.f) ? 1.f : ((s2[kk] < 0.f) ? -1.f : 0.f);
            a = sg1 * e1[kk] * i1 - lam * (sg2 * e2[kk] * i2) + lam * (Gb[j] * (1.f / 1024.f));
        }
        arow[j] = a;
    }
    __syncthreads();
    // V contracted in TOKEN order (reference einsum quirk): V row for attn index j is token j.
    int d = tid & 63, g = tid >> 6;
    const float* Vb = Yv + (size_t)b * 1024 * 1024 + h * 64 + d;
    float part = 0.f;
#pragma unroll 4
    for (int j = g * 256; j < g * 256 + 256; j++) part += arow[j] * Vb[(size_t)j * 1024];
    pr[tid] = part;
    __syncthreads();
    if (tid < 64) {
        float ao = pr[tid] + pr[tid + 64] + pr[tid + 128] + pr[tid + 192];
        float ss = ao * ao;
#pragma unroll
        for (int o = 1; o < 64; o <<= 1) ss += __shfl_xor(ss, o);
        float r = rsqrtf(ss * (1.f / 64.f) + EPS_ATTN);
        float ov = ao * r * wan[tid];
        // ao.reshape(B, S, H*HD): flat = b*2^20 + h*2^16 + q'*64 + d
        aoS[((size_t)b << 20) + ((size_t)h << 16) + ((size_t)qp << 6) + tid] = f2bf(ov);
    }
}

extern "C" void kernel_launch(void* const* d_in, const int* in_sizes, int n_in,
                              void* d_out, int out_size, void* d_ws, size_t ws_size,
                              hipStream_t stream) {
    const float* x    = (const float*)d_in[0];
    const float* fc   = (const float*)d_in[1];
    const float* w1   = (const float*)d_in[2];
    const float* w2   = (const float*)d_in[3];
    const float* Wq   = (const float*)d_in[4];
    const float* bq   = (const float*)d_in[5];
    const float* Wk   = (const float*)d_in[6];
    const float* bk   = (const float*)d_in[7];
    const float* Wv   = (const float*)d_in[8];
    const float* bv   = (const float*)d_in[9];
    const float* Wo   = (const float*)d_in[10];
    const float* bo   = (const float*)d_in[11];
    const float* lq1  = (const float*)d_in[12];
    const float* lk1  = (const float*)d_in[13];
    const float* lq2  = (const float*)d_in[14];
    const float* lk2  = (const float*)d_in[15];
    const float* wan  = (const float*)d_in[16];
    const float* Wg   = (const float*)d_in[17];
    const float* bg   = (const float*)d_in[18];
    const float* Wout = (const float*)d_in[19];
    const float* bout = (const float*)d_in[20];

    char* ws = (char*)d_ws;
    const size_t MB = 1024 * 1024;
    // Layout (peak 33 MB, identical to round 8 which ran cleanly):
    float* G    = (float*)(ws);                     // [0, 128K)
    float* lam  = (float*)(ws + 256 * 1024);        // 4 B
    float* h32  = (float*)(ws + 1 * MB);            // [1,9)   fp32 2048x1024
    float* Yq   = (float*)(ws + 9 * MB);            // [9,17)
    float* Yk   = (float*)(ws + 17 * MB);           // [17,25)
    float* Yv   = (float*)(ws + 25 * MB);           // [25,33)
    unsigned short* aoS = (unsigned short*)(ws + 1 * MB);   // reuse [1,5)  (h32 dead after QKV)
    float* X1           = (float*)(ws + 9 * MB);            // reuse [9,17) (Yq dead after pass_b)
    unsigned short* h2b = (unsigned short*)(ws + 1 * MB);   // reuse [1,5)  (aoS dead after Wo gemm)
    unsigned short* mlp = (unsigned short*)(ws + 17 * MB);  // reuse [17,33) (Yk/Yv dead)

    prep<<<32, 256, 0, stream>>>(G, lam, lq1, lk1, lq2, lk2);
    rms_kernel<0><<<2048, 256, 0, stream>>>(x, w1, h32, EPS_DEF);
    dim3 gqkv(32, 16);
    gemm_v<float, 0><<<gqkv, 256, 0, stream>>>(h32, Wq, bq, nullptr, Yq, 2048, 1024, 1024);
    gemm_v<float, 0><<<gqkv, 256, 0, stream>>>(h32, Wk, bk, nullptr, Yk, 2048, 1024, 1024);
    gemm_v<float, 0><<<gqkv, 256, 0, stream>>>(h32, Wv, bv, nullptr, Yv, 2048, 1024, 1024);
    rope_inplace<<<2048, 256, 0, stream>>>(Yq, fc);
    rope_inplace<<<2048, 256, 0, stream>>>(Yk, fc);
    pass_a<<<dim3(16, 16, 2), 256, 0, stream>>>(Yq, Yk, G);
    pass_b<<<dim3(1024, 16, 2), 256, 0, stream>>>(Yq, Yk, Yv, G, lam, wan, aoS);
    gemm_v<unsigned short, 1><<<gqkv, 256, 0, stream>>>(aoS, Wo, bo, x, X1, 2048, 1024, 1024);
    rms_kernel<1><<<2048, 256, 0, stream>>>(X1, w2, h2b, EPS_DEF);
    gemm_gate_v<<<dim3(32, 64), 256, 0, stream>>>(h2b, Wg, bg, mlp);
    // FINAL OUTPUT IS FP32 (the round-3..8 failure was writing bf16 here).
    gemm_v<unsigned short, 1><<<dim3(32, 16), 256, 0, stream>>>(mlp, Wout, bout, X1, (float*)d_out, 2048, 1024, 4096);
}